// Round 3
// baseline (228.959 us; speedup 1.0000x reference)
//
#include <hip/hip_runtime.h>

// Shapes: (4, 1, 128, 128, 128) fp32. Strides: w=1, h=128, d=16384, n=2097152.
// Total elements N = 8,388,608; float4 count = 2,097,152 = 8192 blocks * 256.

#define TOTAL_F4   2097152
#define INV_N      (1.0f / 8388608.0f)

// Native clang vector type — __builtin_nontemporal_load requires it
// (HIP_vector_type float4 is a struct and is rejected).
typedef float floatx4 __attribute__((ext_vector_type(4)));

__device__ __forceinline__ floatx4 ntload4(const float* p) {
    const floatx4* q = reinterpret_cast<const floatx4*>(p);
    return __builtin_nontemporal_load(q);
}

__device__ __forceinline__ floatx4 load4(const float* p) {
    return *reinterpret_cast<const floatx4*>(p);
}

__global__ __launch_bounds__(256) void fk_loss_kernel(
    const float* __restrict__ u,
    const float* __restrict__ dudt,
    const float* __restrict__ D,
    const float* __restrict__ rho,
    float* __restrict__ out)
{
    const int t = blockIdx.x * blockDim.x + threadIdx.x;   // float4 index

    // Decompose: 32 float4 per row (w), 128 rows (h), 128 planes (d), 4 batches (n)
    const int w4 = t & 31;
    const int h  = (t >> 5) & 127;
    const int d  = (t >> 12) & 127;

    const long base = (long)t * 4;   // element index, 16B-aligned

    const floatx4 c  = load4(u + base);
    const floatx4 dd = ntload4(dudt + base);   // streamed once — don't pollute L2
    const floatx4 Dv = ntload4(D    + base);
    const floatx4 rv = ntload4(rho  + base);

    const floatx4 zero = (floatx4)(0.f);

    // w-direction scalar halo (zero padding at row edges)
    const float left  = (w4 == 0)  ? 0.f : u[base - 1];
    const float right = (w4 == 31) ? 0.f : u[base + 4];

    // h +/- 1 (stride 128 floats = 512 B, stays 16B-aligned)
    const floatx4 hm = (h == 0)   ? zero : load4(u + base - 128);
    const floatx4 hp = (h == 127) ? zero : load4(u + base + 128);

    // d +/- 1 (stride 16384 floats = 64 KB) — never crosses batch boundary
    const floatx4 dm = (d == 0)   ? zero : load4(u + base - 16384);
    const floatx4 dp = (d == 127) ? zero : load4(u + base + 16384);

    // 7-point Laplacian per element (VOXEL_SPACING = 1)
    float lap[4];
    lap[0] = left + c.y + hm.x + hp.x + dm.x + dp.x - 6.0f * c.x;
    lap[1] = c.x  + c.z + hm.y + hp.y + dm.y + dp.y - 6.0f * c.y;
    lap[2] = c.y  + c.w + hm.z + hp.z + dm.z + dp.z - 6.0f * c.z;
    lap[3] = c.z + right + hm.w + hp.w + dm.w + dp.w - 6.0f * c.w;

    const float cc[4]  = {c.x, c.y, c.z, c.w};
    const float dda[4] = {dd.x, dd.y, dd.z, dd.w};
    const float Da[4]  = {Dv.x, Dv.y, Dv.z, Dv.w};
    const float ra[4]  = {rv.x, rv.y, rv.z, rv.w};

    float partial = 0.f;
#pragma unroll
    for (int i = 0; i < 4; ++i) {
        const float reaction = ra[i] * cc[i] * (1.0f - cc[i]);
        const float residual = dda[i] - (Da[i] * lap[i] + reaction);
        partial += residual * residual;
    }
    partial *= INV_N;

    // Wave-64 reduction
#pragma unroll
    for (int off = 32; off > 0; off >>= 1)
        partial += __shfl_down(partial, off);

    __shared__ float smem[4];   // 256 threads = 4 waves
    const int lane = threadIdx.x & 63;
    const int wid  = threadIdx.x >> 6;
    if (lane == 0) smem[wid] = partial;
    __syncthreads();

    if (threadIdx.x == 0) {
        const float s = (smem[0] + smem[1]) + (smem[2] + smem[3]);
        atomicAdd(out, s);
    }
}

extern "C" void kernel_launch(void* const* d_in, const int* in_sizes, int n_in,
                              void* d_out, int out_size, void* d_ws, size_t ws_size,
                              hipStream_t stream) {
    const float* u    = (const float*)d_in[0];
    const float* dudt = (const float*)d_in[1];
    const float* D    = (const float*)d_in[2];
    const float* rho  = (const float*)d_in[3];
    float* out = (float*)d_out;

    // d_out is poisoned to 0xAA before every timed launch — zero it.
    (void)hipMemsetAsync(out, 0, sizeof(float), stream);

    const int threads = 256;
    const int blocks  = TOTAL_F4 / threads;   // 8192
    fk_loss_kernel<<<blocks, threads, 0, stream>>>(u, dudt, D, rho, out);
}

// Round 6
// 145.327 us; speedup vs baseline: 1.5755x; 1.5755x over previous
//
#include <hip/hip_runtime.h>

// Shapes: (4, 1, 128, 128, 128) fp32. Strides: w=1, h=128, d=16384, n=2097152.
// Total elements N = 8,388,608; float4 count = 2,097,152 = 8192 blocks * 256.

#define TOTAL_F4     2097152
#define NUM_BLOCKS   8192
#define INV_N        (1.0f / 8388608.0f)

// Native clang vector type — __builtin_nontemporal_load requires it.
typedef float floatx4 __attribute__((ext_vector_type(4)));

__device__ __forceinline__ floatx4 ntload4(const float* p) {
    const floatx4* q = reinterpret_cast<const floatx4*>(p);
    return __builtin_nontemporal_load(q);
}

__device__ __forceinline__ floatx4 load4(const float* p) {
    return *reinterpret_cast<const floatx4*>(p);
}

// Stage 1: fused stencil + reaction + residual^2, block partial -> partials[bid].
// NO atomics (round-3 postmortem: 8192 same-address atomicAdds serialized ~107us).
__global__ __launch_bounds__(256) void fk_loss_kernel(
    const float* __restrict__ u,
    const float* __restrict__ dudt,
    const float* __restrict__ D,
    const float* __restrict__ rho,
    float* __restrict__ partials)
{
    const int t = blockIdx.x * blockDim.x + threadIdx.x;   // float4 index

    // Decompose: 32 float4 per row (w), 128 rows (h), 128 planes (d), 4 batches (n)
    const int w4 = t & 31;
    const int h  = (t >> 5) & 127;
    const int d  = (t >> 12) & 127;

    const long base = (long)t * 4;   // element index, 16B-aligned

    const floatx4 c  = load4(u + base);
    const floatx4 dd = ntload4(dudt + base);   // streamed once — don't pollute L2
    const floatx4 Dv = ntload4(D    + base);
    const floatx4 rv = ntload4(rho  + base);

    const floatx4 zero = (floatx4)(0.f);

    // w-direction scalar halo (zero padding at row edges)
    const float left  = (w4 == 0)  ? 0.f : u[base - 1];
    const float right = (w4 == 31) ? 0.f : u[base + 4];

    // h +/- 1 (stride 128 floats = 512 B, stays 16B-aligned)
    const floatx4 hm = (h == 0)   ? zero : load4(u + base - 128);
    const floatx4 hp = (h == 127) ? zero : load4(u + base + 128);

    // d +/- 1 (stride 16384 floats = 64 KB) — never crosses batch boundary
    const floatx4 dm = (d == 0)   ? zero : load4(u + base - 16384);
    const floatx4 dp = (d == 127) ? zero : load4(u + base + 16384);

    // 7-point Laplacian per element (VOXEL_SPACING = 1)
    float lap[4];
    lap[0] = left + c.y + hm.x + hp.x + dm.x + dp.x - 6.0f * c.x;
    lap[1] = c.x  + c.z + hm.y + hp.y + dm.y + dp.y - 6.0f * c.y;
    lap[2] = c.y  + c.w + hm.z + hp.z + dm.z + dp.z - 6.0f * c.z;
    lap[3] = c.z + right + hm.w + hp.w + dm.w + dp.w - 6.0f * c.w;

    const float cc[4]  = {c.x, c.y, c.z, c.w};
    const float dda[4] = {dd.x, dd.y, dd.z, dd.w};
    const float Da[4]  = {Dv.x, Dv.y, Dv.z, Dv.w};
    const float ra[4]  = {rv.x, rv.y, rv.z, rv.w};

    float partial = 0.f;
#pragma unroll
    for (int i = 0; i < 4; ++i) {
        const float reaction = ra[i] * cc[i] * (1.0f - cc[i]);
        const float residual = dda[i] - (Da[i] * lap[i] + reaction);
        partial += residual * residual;
    }

    // Wave-64 reduction
#pragma unroll
    for (int off = 32; off > 0; off >>= 1)
        partial += __shfl_down(partial, off);

    __shared__ float smem[4];   // 256 threads = 4 waves
    const int lane = threadIdx.x & 63;
    const int wid  = threadIdx.x >> 6;
    if (lane == 0) smem[wid] = partial;
    __syncthreads();

    if (threadIdx.x == 0)
        partials[blockIdx.x] = (smem[0] + smem[1]) + (smem[2] + smem[3]);
}

// Stage 2: one block sums NUM_BLOCKS partials, writes out directly (no memset).
__global__ __launch_bounds__(1024) void fk_reduce_kernel(
    const float* __restrict__ partials, float* __restrict__ out)
{
    float s = 0.f;
#pragma unroll
    for (int i = 0; i < NUM_BLOCKS / 1024; ++i)
        s += partials[threadIdx.x + i * 1024];

#pragma unroll
    for (int off = 32; off > 0; off >>= 1)
        s += __shfl_down(s, off);

    __shared__ float smem[16];   // 1024 threads = 16 waves
    const int lane = threadIdx.x & 63;
    const int wid  = threadIdx.x >> 6;
    if (lane == 0) smem[wid] = s;
    __syncthreads();

    if (threadIdx.x == 0) {
        float t = 0.f;
#pragma unroll
        for (int i = 0; i < 16; ++i) t += smem[i];
        out[0] = t * INV_N;
    }
}

extern "C" void kernel_launch(void* const* d_in, const int* in_sizes, int n_in,
                              void* d_out, int out_size, void* d_ws, size_t ws_size,
                              hipStream_t stream) {
    const float* u    = (const float*)d_in[0];
    const float* dudt = (const float*)d_in[1];
    const float* D    = (const float*)d_in[2];
    const float* rho  = (const float*)d_in[3];
    float* out      = (float*)d_out;
    float* partials = (float*)d_ws;   // 8192 floats = 32 KB scratch

    fk_loss_kernel<<<NUM_BLOCKS, 256, 0, stream>>>(u, dudt, D, rho, partials);
    fk_reduce_kernel<<<1, 1024, 0, stream>>>(partials, out);
}